// Round 1
// baseline (596.765 us; speedup 1.0000x reference)
//
#include <hip/hip_runtime.h>
#include <math.h>

#define N_NODES 50000
#define N_EDGES 800000
#define N_GRAPHS 128
#define DIM0 256
#define DIM1 128
#define DIM2 32

// ---------------- init: zero the accumulators we need ----------------
__global__ __launch_bounds__(256) void k_init(int* cnt, float* pooled, float* cntg) {
    int i = blockIdx.x * 256 + threadIdx.x;
    if (i < N_NODES) cnt[i] = 0;
    if (i < N_GRAPHS * DIM2) pooled[i] = 0.f;
    if (i < N_GRAPHS) cntg[i] = 0.f;
}

// ---------------- count edges per destination (row) ----------------
__global__ __launch_bounds__(256) void k_count(const int* __restrict__ row, int* cnt) {
    int e = blockIdx.x * 256 + threadIdx.x;
    if (e < N_EDGES) atomicAdd(&cnt[row[e]], 1);
}

// ---------------- dinv = rsqrt(cnt + 1)  (self-loop) ----------------
__global__ __launch_bounds__(256) void k_dinv(const int* __restrict__ cnt, float* dinv) {
    int i = blockIdx.x * 256 + threadIdx.x;
    if (i < N_NODES) dinv[i] = rsqrtf((float)(cnt[i] + 1));
}

// ---------------- graph node counts ----------------
__global__ __launch_bounds__(256) void k_nodecnt(const int* __restrict__ batch, float* cntg) {
    int i = blockIdx.x * 256 + threadIdx.x;
    if (i < N_NODES) atomicAdd(&cntg[batch[i]], 1.0f);
}

// ---------------- exclusive scan of cnt -> offs (3 phases) ----------------
// phase A: per-block (1024 elems) exclusive scan + block sums
__global__ __launch_bounds__(256) void k_scan_a(const int* __restrict__ cnt, int* offs, int* bsums) {
    __shared__ int s[256];
    int b = blockIdx.x, t = threadIdx.x;
    int base = b * 1024 + t * 4;
    int v[4];
#pragma unroll
    for (int j = 0; j < 4; ++j) v[j] = (base + j < N_NODES) ? cnt[base + j] : 0;
    int local = v[0] + v[1] + v[2] + v[3];
    s[t] = local;
    __syncthreads();
    for (int off = 1; off < 256; off <<= 1) {
        int x = (t >= off) ? s[t - off] : 0;
        __syncthreads();
        s[t] += x;
        __syncthreads();
    }
    int run = s[t] - local;  // exclusive
#pragma unroll
    for (int j = 0; j < 4; ++j) {
        if (base + j < N_NODES) offs[base + j] = run;
        run += v[j];
    }
    if (t == 255) bsums[b] = s[255];
}

// phase B: serial exclusive scan of block sums (49 values)
__global__ void k_scan_b(int* bsums, int nb) {
    if (threadIdx.x == 0 && blockIdx.x == 0) {
        int run = 0;
        for (int i = 0; i < nb; ++i) { int t = bsums[i]; bsums[i] = run; run += t; }
    }
}

// phase C: add block offsets; init cursor
__global__ __launch_bounds__(256) void k_scan_c(int* offs, const int* __restrict__ bsums, int* cursor) {
    int i = blockIdx.x * 256 + threadIdx.x;
    if (i < N_NODES) {
        int o = offs[i] + bsums[i >> 10];
        offs[i] = o;
        cursor[i] = o;
    }
}

// ---------------- fill CSR columns ----------------
__global__ __launch_bounds__(256) void k_fill(const int* __restrict__ row, const int* __restrict__ col,
                                              int* cursor, int* csr) {
    int e = blockIdx.x * 256 + threadIdx.x;
    if (e < N_EDGES) {
        int r = row[e];
        int pos = atomicAdd(&cursor[r], 1);
        csr[pos] = col[e];
    }
}

// ---------------- GEMM1: H[50000,128] = X[50000,256] @ W[256,128] ----------------
#define BM 64
#define BK 16
__global__ __launch_bounds__(256) void k_gemm1(const float* __restrict__ X, const float* __restrict__ W,
                                               float* __restrict__ H) {
    __shared__ float As[BM][BK + 1];
    __shared__ float Bs[BK][DIM1];
    int t = threadIdx.x;
    int tx = t & 15, ty = t >> 4;
    int rowBase = blockIdx.x * BM;
    float acc[4][8];
#pragma unroll
    for (int i = 0; i < 4; ++i)
#pragma unroll
        for (int j = 0; j < 8; ++j) acc[i][j] = 0.f;

    int ar = t >> 2, ak = (t & 3) * 4;        // A load: 64 rows x 16 k, float4
    int bk = t >> 4, bn = (t & 15) * 8;       // B load: 16 k x 128 n, 2x float4

    for (int k0 = 0; k0 < DIM0; k0 += BK) {
        int grow = rowBase + ar;
        float4 av = make_float4(0.f, 0.f, 0.f, 0.f);
        if (grow < N_NODES) av = *(const float4*)(X + (size_t)grow * DIM0 + k0 + ak);
        float4 bv0 = *(const float4*)(W + (size_t)(k0 + bk) * DIM1 + bn);
        float4 bv1 = *(const float4*)(W + (size_t)(k0 + bk) * DIM1 + bn + 4);
        __syncthreads();
        As[ar][ak + 0] = av.x; As[ar][ak + 1] = av.y; As[ar][ak + 2] = av.z; As[ar][ak + 3] = av.w;
        *(float4*)&Bs[bk][bn] = bv0;
        *(float4*)&Bs[bk][bn + 4] = bv1;
        __syncthreads();
#pragma unroll
        for (int kk = 0; kk < BK; ++kk) {
            float4 b0 = *(const float4*)&Bs[kk][tx * 4];
            float4 b1v = *(const float4*)&Bs[kk][64 + tx * 4];
#pragma unroll
            for (int i = 0; i < 4; ++i) {
                float a_ = As[ty * 4 + i][kk];
                acc[i][0] += a_ * b0.x;  acc[i][1] += a_ * b0.y;
                acc[i][2] += a_ * b0.z;  acc[i][3] += a_ * b0.w;
                acc[i][4] += a_ * b1v.x; acc[i][5] += a_ * b1v.y;
                acc[i][6] += a_ * b1v.z; acc[i][7] += a_ * b1v.w;
            }
        }
    }
#pragma unroll
    for (int i = 0; i < 4; ++i) {
        int row = rowBase + ty * 4 + i;
        if (row < N_NODES) {
            float4 o0 = make_float4(acc[i][0], acc[i][1], acc[i][2], acc[i][3]);
            float4 o1 = make_float4(acc[i][4], acc[i][5], acc[i][6], acc[i][7]);
            *(float4*)(H + (size_t)row * DIM1 + tx * 4) = o0;
            *(float4*)(H + (size_t)row * DIM1 + 64 + tx * 4) = o1;
        }
    }
}

// ---------------- agg1: a1 = relu(Anorm @ h1 + b1), dim 128 ----------------
__global__ __launch_bounds__(256) void k_agg1(const float* __restrict__ h1, const float* __restrict__ dinv,
                                              const int* __restrict__ offs, const int* __restrict__ cnt,
                                              const int* __restrict__ csr, const float* __restrict__ b1,
                                              float* __restrict__ a1) {
    int node = blockIdx.x * 4 + (threadIdx.x >> 6);
    if (node >= N_NODES) return;
    int lane = threadIdx.x & 63;
    float di = dinv[node];
    const float2* h1v = (const float2*)h1;  // 64 float2 per row
    float2 acc = h1v[(size_t)node * 64 + lane];
    float sl = di * di;
    acc.x *= sl; acc.y *= sl;
    int s = offs[node], e = s + cnt[node];
    for (int i = s; i < e; ++i) {
        int c = csr[i];
        float w = di * dinv[c];
        float2 hv = h1v[(size_t)c * 64 + lane];
        acc.x += hv.x * w;
        acc.y += hv.y * w;
    }
    acc.x = fmaxf(acc.x + b1[2 * lane], 0.f);
    acc.y = fmaxf(acc.y + b1[2 * lane + 1], 0.f);
    ((float2*)a1)[(size_t)node * 64 + lane] = acc;
}

// ---------------- GEMM2: h2[50000,32] = a1[50000,128] @ W2[128,32] ----------------
__global__ __launch_bounds__(256) void k_gemm2(const float* __restrict__ A, const float* __restrict__ W2,
                                               float* __restrict__ H2) {
    __shared__ float As2[8 * DIM1];       // 8 rows x 128
    __shared__ float W2s[DIM1 * DIM2];    // 128 x 32
    int t = threadIdx.x;
    int rb = blockIdx.x * 8;
    // load A tile: 1024 floats = 256 threads x float4
    {
        int grow = rb + (t >> 5);
        int c = (t & 31) * 4;
        float4 v = make_float4(0.f, 0.f, 0.f, 0.f);
        if (grow < N_NODES) v = *(const float4*)(A + (size_t)grow * DIM1 + c);
        *(float4*)&As2[(t >> 5) * DIM1 + c] = v;
    }
    // load W2: 4096 floats
    for (int i = t; i < 1024; i += 256) {
        *(float4*)&W2s[i * 4] = *(const float4*)(W2 + i * 4);
    }
    __syncthreads();
    int r = t >> 5, col = t & 31;
    float acc = 0.f;
#pragma unroll 8
    for (int k = 0; k < DIM1; ++k) acc += As2[r * DIM1 + k] * W2s[k * DIM2 + col];
    int row = rb + r;
    if (row < N_NODES) H2[(size_t)row * DIM2 + col] = acc;
}

// ---------------- agg2 + mean-pool accumulation (dim 32) ----------------
__global__ __launch_bounds__(256) void k_agg2(const float* __restrict__ h2, const float* __restrict__ dinv,
                                              const int* __restrict__ offs, const int* __restrict__ cnt,
                                              const int* __restrict__ csr, const float* __restrict__ b2,
                                              const int* __restrict__ batch, float* pooled) {
    int lane = threadIdx.x & 63;
    int node = blockIdx.x * 8 + (threadIdx.x >> 6) * 2 + (lane >> 5);
    if (node >= N_NODES) return;
    int d = lane & 31;
    float di = dinv[node];
    float acc = h2[(size_t)node * DIM2 + d] * di * di;
    int s = offs[node], e = s + cnt[node];
    for (int i = s; i < e; ++i) {
        int c = csr[i];
        acc += h2[(size_t)c * DIM2 + d] * (di * dinv[c]);
    }
    acc += b2[d];
    atomicAdd(&pooled[batch[node] * DIM2 + d], acc);
}

// ---------------- mean + log_softmax ----------------
__global__ __launch_bounds__(256) void k_final(const float* __restrict__ pooled, const float* __restrict__ cntg,
                                               float* __restrict__ out) {
    int g = blockIdx.x * 4 + (threadIdx.x >> 6);
    int lane = threadIdx.x & 63;
    if (g >= N_GRAPHS) return;
    float val = 0.f, v = -INFINITY;
    if (lane < DIM2) {
        val = pooled[g * DIM2 + lane] / fmaxf(cntg[g], 1.0f);
        v = val;
    }
#pragma unroll
    for (int m = 16; m >= 1; m >>= 1) v = fmaxf(v, __shfl_xor(v, m, 32));
    float ex = (lane < DIM2) ? expf(val - v) : 0.f;
#pragma unroll
    for (int m = 16; m >= 1; m >>= 1) ex += __shfl_xor(ex, m, 32);
    if (lane < DIM2) out[g * DIM2 + lane] = val - v - logf(ex);
}

extern "C" void kernel_launch(void* const* d_in, const int* in_sizes, int n_in,
                              void* d_out, int out_size, void* d_ws, size_t ws_size,
                              hipStream_t stream) {
    const float* x     = (const float*)d_in[0];
    const int*   eidx  = (const int*)d_in[1];
    const int*   batch = (const int*)d_in[2];
    const float* W1    = (const float*)d_in[3];
    const float* b1    = (const float*)d_in[4];
    const float* W2    = (const float*)d_in[5];
    const float* b2    = (const float*)d_in[6];
    const int* row = eidx;
    const int* col = eidx + N_EDGES;
    float* out = (float*)d_out;

    // workspace layout (16B aligned chunks)
    char* p = (char*)d_ws;
    float* dinv   = (float*)p; p += (size_t)N_NODES * 4;          // 200000
    int*   cnt    = (int*)p;   p += (size_t)N_NODES * 4;
    int*   offs   = (int*)p;   p += (size_t)N_NODES * 4;
    int*   cursor = (int*)p;   p += (size_t)N_NODES * 4;
    int*   bsums  = (int*)p;   p += 256;
    int*   csr    = (int*)p;   p += (size_t)N_EDGES * 4;
    float* h1     = (float*)p; p += (size_t)N_NODES * DIM1 * 4;
    float* a1     = (float*)p; p += (size_t)N_NODES * DIM1 * 4;
    float* h2     = (float*)p; p += (size_t)N_NODES * DIM2 * 4;
    float* pooled = (float*)p; p += (size_t)N_GRAPHS * DIM2 * 4;
    float* cntg   = (float*)p; p += 512;

    const int nb_nodes = (N_NODES + 255) / 256;       // 196
    const int nb_edges = (N_EDGES + 255) / 256;       // 3125
    const int nb_scan  = (N_NODES + 1023) / 1024;     // 49

    k_init<<<nb_nodes, 256, 0, stream>>>(cnt, pooled, cntg);
    k_count<<<nb_edges, 256, 0, stream>>>(row, cnt);
    k_dinv<<<nb_nodes, 256, 0, stream>>>(cnt, dinv);
    k_nodecnt<<<nb_nodes, 256, 0, stream>>>(batch, cntg);
    k_scan_a<<<nb_scan, 256, 0, stream>>>(cnt, offs, bsums);
    k_scan_b<<<1, 64, 0, stream>>>(bsums, nb_scan);
    k_scan_c<<<nb_nodes, 256, 0, stream>>>(offs, bsums, cursor);
    k_fill<<<nb_edges, 256, 0, stream>>>(row, col, cursor, csr);

    k_gemm1<<<(N_NODES + BM - 1) / BM, 256, 0, stream>>>(x, W1, h1);
    k_agg1<<<(N_NODES + 3) / 4, 256, 0, stream>>>(h1, dinv, offs, cnt, csr, b1, a1);
    k_gemm2<<<(N_NODES + 7) / 8, 256, 0, stream>>>(a1, W2, h2);
    k_agg2<<<(N_NODES + 7) / 8, 256, 0, stream>>>(h2, dinv, offs, cnt, csr, b2, batch, pooled);
    k_final<<<(N_GRAPHS + 3) / 4, 256, 0, stream>>>(pooled, cntg, out);
}

// Round 2
// 415.429 us; speedup vs baseline: 1.4365x; 1.4365x over previous
//
#include <hip/hip_runtime.h>
#include <math.h>

#define N_NODES 50000
#define N_EDGES 800000
#define N_GRAPHS 128
#define DIM0 256
#define DIM1 128
#define DIM2 32

// ---------------- init: zero edge counters ----------------
__global__ __launch_bounds__(256) void k_init(int* cnt) {
    int i = blockIdx.x * 256 + threadIdx.x;
    if (i < N_NODES) cnt[i] = 0;
}

// ---------------- count edges per destination (row) ----------------
__global__ __launch_bounds__(256) void k_count(const int* __restrict__ row, int* cnt) {
    int e = blockIdx.x * 256 + threadIdx.x;
    if (e < N_EDGES) atomicAdd(&cnt[row[e]], 1);
}

// ---------------- dinv = rsqrt(cnt + 1)  (self-loop) ----------------
__global__ __launch_bounds__(256) void k_dinv(const int* __restrict__ cnt, float* dinv) {
    int i = blockIdx.x * 256 + threadIdx.x;
    if (i < N_NODES) dinv[i] = rsqrtf((float)(cnt[i] + 1));
}

// ---------------- graph start offsets via binary search (batch is sorted) ----------------
__global__ __launch_bounds__(256) void k_gbounds(const int* __restrict__ batch, int* gstart) {
    int g = blockIdx.x * 256 + threadIdx.x;
    if (g <= N_GRAPHS) {
        int lo = 0, hi = N_NODES;
        while (lo < hi) { int mid = (lo + hi) >> 1; if (batch[mid] < g) lo = mid + 1; else hi = mid; }
        gstart[g] = lo;
    }
}

// ---------------- exclusive scan of cnt -> offs (3 phases) ----------------
__global__ __launch_bounds__(256) void k_scan_a(const int* __restrict__ cnt, int* offs, int* bsums) {
    __shared__ int s[256];
    int b = blockIdx.x, t = threadIdx.x;
    int base = b * 1024 + t * 4;
    int v[4];
#pragma unroll
    for (int j = 0; j < 4; ++j) v[j] = (base + j < N_NODES) ? cnt[base + j] : 0;
    int local = v[0] + v[1] + v[2] + v[3];
    s[t] = local;
    __syncthreads();
    for (int off = 1; off < 256; off <<= 1) {
        int x = (t >= off) ? s[t - off] : 0;
        __syncthreads();
        s[t] += x;
        __syncthreads();
    }
    int run = s[t] - local;  // exclusive
#pragma unroll
    for (int j = 0; j < 4; ++j) {
        if (base + j < N_NODES) offs[base + j] = run;
        run += v[j];
    }
    if (t == 255) bsums[b] = s[255];
}

__global__ void k_scan_b(int* bsums, int nb) {
    if (threadIdx.x == 0 && blockIdx.x == 0) {
        int run = 0;
        for (int i = 0; i < nb; ++i) { int t = bsums[i]; bsums[i] = run; run += t; }
    }
}

__global__ __launch_bounds__(256) void k_scan_c(int* offs, const int* __restrict__ bsums, int* cursor) {
    int i = blockIdx.x * 256 + threadIdx.x;
    if (i < N_NODES) {
        int o = offs[i] + bsums[i >> 10];
        offs[i] = o;
        cursor[i] = o;
    }
}

// ---------------- fill CSR columns ----------------
__global__ __launch_bounds__(256) void k_fill(const int* __restrict__ row, const int* __restrict__ col,
                                              int* cursor, int* csr) {
    int e = blockIdx.x * 256 + threadIdx.x;
    if (e < N_EDGES) {
        int r = row[e];
        int pos = atomicAdd(&cursor[r], 1);
        csr[pos] = col[e];
    }
}

// ---------------- GEMM1: H[50000,128] = X[50000,256] @ W[256,128] ----------------
#define BM 64
#define BK 16
__global__ __launch_bounds__(256) void k_gemm1(const float* __restrict__ X, const float* __restrict__ W,
                                               float* __restrict__ H) {
    __shared__ float As[BM][BK + 1];
    __shared__ float Bs[BK][DIM1];
    int t = threadIdx.x;
    int tx = t & 15, ty = t >> 4;
    int rowBase = blockIdx.x * BM;
    float acc[4][8];
#pragma unroll
    for (int i = 0; i < 4; ++i)
#pragma unroll
        for (int j = 0; j < 8; ++j) acc[i][j] = 0.f;

    int ar = t >> 2, ak = (t & 3) * 4;        // A load: 64 rows x 16 k, float4
    int bk = t >> 4, bn = (t & 15) * 8;       // B load: 16 k x 128 n, 2x float4

    for (int k0 = 0; k0 < DIM0; k0 += BK) {
        int grow = rowBase + ar;
        float4 av = make_float4(0.f, 0.f, 0.f, 0.f);
        if (grow < N_NODES) av = *(const float4*)(X + (size_t)grow * DIM0 + k0 + ak);
        float4 bv0 = *(const float4*)(W + (size_t)(k0 + bk) * DIM1 + bn);
        float4 bv1 = *(const float4*)(W + (size_t)(k0 + bk) * DIM1 + bn + 4);
        __syncthreads();
        As[ar][ak + 0] = av.x; As[ar][ak + 1] = av.y; As[ar][ak + 2] = av.z; As[ar][ak + 3] = av.w;
        *(float4*)&Bs[bk][bn] = bv0;
        *(float4*)&Bs[bk][bn + 4] = bv1;
        __syncthreads();
#pragma unroll
        for (int kk = 0; kk < BK; ++kk) {
            float4 b0 = *(const float4*)&Bs[kk][tx * 4];
            float4 b1v = *(const float4*)&Bs[kk][64 + tx * 4];
#pragma unroll
            for (int i = 0; i < 4; ++i) {
                float a_ = As[ty * 4 + i][kk];
                acc[i][0] += a_ * b0.x;  acc[i][1] += a_ * b0.y;
                acc[i][2] += a_ * b0.z;  acc[i][3] += a_ * b0.w;
                acc[i][4] += a_ * b1v.x; acc[i][5] += a_ * b1v.y;
                acc[i][6] += a_ * b1v.z; acc[i][7] += a_ * b1v.w;
            }
        }
    }
#pragma unroll
    for (int i = 0; i < 4; ++i) {
        int row = rowBase + ty * 4 + i;
        if (row < N_NODES) {
            float4 o0 = make_float4(acc[i][0], acc[i][1], acc[i][2], acc[i][3]);
            float4 o1 = make_float4(acc[i][4], acc[i][5], acc[i][6], acc[i][7]);
            *(float4*)(H + (size_t)row * DIM1 + tx * 4) = o0;
            *(float4*)(H + (size_t)row * DIM1 + 64 + tx * 4) = o1;
        }
    }
}

// ---------------- agg1: a1 = relu(Anorm @ h1 + b1), dim 128 ----------------
__global__ __launch_bounds__(256) void k_agg1(const float* __restrict__ h1, const float* __restrict__ dinv,
                                              const int* __restrict__ offs, const int* __restrict__ cnt,
                                              const int* __restrict__ csr, const float* __restrict__ b1,
                                              float* __restrict__ a1) {
    int node = blockIdx.x * 4 + (threadIdx.x >> 6);
    if (node >= N_NODES) return;
    int lane = threadIdx.x & 63;
    float di = dinv[node];
    const float2* h1v = (const float2*)h1;  // 64 float2 per row
    float2 acc = h1v[(size_t)node * 64 + lane];
    float sl = di * di;
    acc.x *= sl; acc.y *= sl;
    int s = offs[node], e = s + cnt[node];
    for (int i = s; i < e; ++i) {
        int c = csr[i];
        float w = di * dinv[c];
        float2 hv = h1v[(size_t)c * 64 + lane];
        acc.x += hv.x * w;
        acc.y += hv.y * w;
    }
    acc.x = fmaxf(acc.x + b1[2 * lane], 0.f);
    acc.y = fmaxf(acc.y + b1[2 * lane + 1], 0.f);
    ((float2*)a1)[(size_t)node * 64 + lane] = acc;
}

// ---------------- GEMM2: h2[50000,32] = a1[50000,128] @ W2[128,32] ----------------
__global__ __launch_bounds__(256) void k_gemm2(const float* __restrict__ A, const float* __restrict__ W2,
                                               float* __restrict__ H2) {
    __shared__ float As2[8 * DIM1];       // 8 rows x 128
    __shared__ float W2s[DIM1 * DIM2];    // 128 x 32
    int t = threadIdx.x;
    int rb = blockIdx.x * 8;
    {
        int grow = rb + (t >> 5);
        int c = (t & 31) * 4;
        float4 v = make_float4(0.f, 0.f, 0.f, 0.f);
        if (grow < N_NODES) v = *(const float4*)(A + (size_t)grow * DIM1 + c);
        *(float4*)&As2[(t >> 5) * DIM1 + c] = v;
    }
    for (int i = t; i < 1024; i += 256) {
        *(float4*)&W2s[i * 4] = *(const float4*)(W2 + i * 4);
    }
    __syncthreads();
    int r = t >> 5, col = t & 31;
    float acc = 0.f;
#pragma unroll 8
    for (int k = 0; k < DIM1; ++k) acc += As2[r * DIM1 + k] * W2s[k * DIM2 + col];
    int row = rb + r;
    if (row < N_NODES) H2[(size_t)row * DIM2 + col] = acc;
}

// ---------------- agg2: a2 = Anorm @ h2 + b2, plain stores (no atomics) ----------------
__global__ __launch_bounds__(256) void k_agg2(const float* __restrict__ h2, const float* __restrict__ dinv,
                                              const int* __restrict__ offs, const int* __restrict__ cnt,
                                              const int* __restrict__ csr, const float* __restrict__ b2,
                                              float* __restrict__ a2) {
    int lane = threadIdx.x & 63;
    int node = blockIdx.x * 8 + (threadIdx.x >> 6) * 2 + (lane >> 5);
    if (node >= N_NODES) return;
    int d = lane & 31;
    float di = dinv[node];
    float acc = h2[(size_t)node * DIM2 + d] * di * di;
    int s = offs[node], e = s + cnt[node];
    for (int i = s; i < e; ++i) {
        int c = csr[i];
        acc += h2[(size_t)c * DIM2 + d] * (di * dinv[c]);
    }
    a2[(size_t)node * DIM2 + d] = acc + b2[d];
}

// ---------------- segmented mean-pool + log_softmax (1 block / graph) ----------------
__global__ __launch_bounds__(256) void k_pool(const float* __restrict__ a2, const int* __restrict__ gstart,
                                              float* __restrict__ out) {
    __shared__ float sred[8][DIM2];
    int g = blockIdx.x;
    int t = threadIdx.x;
    int s = gstart[g], e = gstart[g + 1];
    int d = t & 31, r = t >> 5;
    float acc = 0.f;
    for (int i = s + r; i < e; i += 8) acc += a2[(size_t)i * DIM2 + d];
    sred[r][d] = acc;
    __syncthreads();
    if (t < DIM2) {
        float sum = 0.f;
#pragma unroll
        for (int j = 0; j < 8; ++j) sum += sred[j][t];
        float cntf = fmaxf((float)(e - s), 1.0f);
        float val = sum / cntf;
        float v = val;
#pragma unroll
        for (int m = 16; m >= 1; m >>= 1) v = fmaxf(v, __shfl_xor(v, m, 32));
        float ex = expf(val - v);
#pragma unroll
        for (int m = 16; m >= 1; m >>= 1) ex += __shfl_xor(ex, m, 32);
        out[g * DIM2 + t] = val - v - logf(ex);
    }
}

extern "C" void kernel_launch(void* const* d_in, const int* in_sizes, int n_in,
                              void* d_out, int out_size, void* d_ws, size_t ws_size,
                              hipStream_t stream) {
    const float* x     = (const float*)d_in[0];
    const int*   eidx  = (const int*)d_in[1];
    const int*   batch = (const int*)d_in[2];
    const float* W1    = (const float*)d_in[3];
    const float* b1    = (const float*)d_in[4];
    const float* W2    = (const float*)d_in[5];
    const float* b2    = (const float*)d_in[6];
    const int* row = eidx;
    const int* col = eidx + N_EDGES;
    float* out = (float*)d_out;

    // workspace layout (16B aligned chunks)
    char* p = (char*)d_ws;
    float* dinv   = (float*)p; p += (size_t)N_NODES * 4;
    int*   cnt    = (int*)p;   p += (size_t)N_NODES * 4;
    int*   offs   = (int*)p;   p += (size_t)N_NODES * 4;
    int*   cursor = (int*)p;   p += (size_t)N_NODES * 4;
    int*   bsums  = (int*)p;   p += 256;
    int*   gstart = (int*)p;   p += 768;  // 129 ints, padded
    int*   csr    = (int*)p;   p += (size_t)N_EDGES * 4;
    float* h1     = (float*)p; p += (size_t)N_NODES * DIM1 * 4;
    float* a1     = (float*)p; p += (size_t)N_NODES * DIM1 * 4;
    float* h2     = (float*)p; p += (size_t)N_NODES * DIM2 * 4;
    float* a2     = h1;  // h1 is dead after k_agg1; reuse for a2

    const int nb_nodes = (N_NODES + 255) / 256;       // 196
    const int nb_edges = (N_EDGES + 255) / 256;       // 3125
    const int nb_scan  = (N_NODES + 1023) / 1024;     // 49

    k_init<<<nb_nodes, 256, 0, stream>>>(cnt);
    k_count<<<nb_edges, 256, 0, stream>>>(row, cnt);
    k_dinv<<<nb_nodes, 256, 0, stream>>>(cnt, dinv);
    k_gbounds<<<1, 256, 0, stream>>>(batch, gstart);
    k_scan_a<<<nb_scan, 256, 0, stream>>>(cnt, offs, bsums);
    k_scan_b<<<1, 64, 0, stream>>>(bsums, nb_scan);
    k_scan_c<<<nb_nodes, 256, 0, stream>>>(offs, bsums, cursor);
    k_fill<<<nb_edges, 256, 0, stream>>>(row, col, cursor, csr);

    k_gemm1<<<(N_NODES + BM - 1) / BM, 256, 0, stream>>>(x, W1, h1);
    k_agg1<<<(N_NODES + 3) / 4, 256, 0, stream>>>(h1, dinv, offs, cnt, csr, b1, a1);
    k_gemm2<<<(N_NODES + 7) / 8, 256, 0, stream>>>(a1, W2, h2);
    k_agg2<<<(N_NODES + 7) / 8, 256, 0, stream>>>(h2, dinv, offs, cnt, csr, b2, a2);
    k_pool<<<N_GRAPHS, 256, 0, stream>>>(a2, gstart, out);
}

// Round 3
// 337.794 us; speedup vs baseline: 1.7667x; 1.2298x over previous
//
#include <hip/hip_runtime.h>
#include <math.h>

#define N_NODES 50000
#define N_EDGES 800000
#define N_GRAPHS 128
#define DIM0 256
#define DIM1 128
#define DIM2 32

// ---- bf16 pack/unpack helpers (RNE) ----
__device__ inline unsigned bf16pack(float a, float b) {
    unsigned ua = __float_as_uint(a), ub = __float_as_uint(b);
    ua = (ua + 0x7fffu + ((ua >> 16) & 1u)) >> 16;
    ub = (ub + 0x7fffu + ((ub >> 16) & 1u)) >> 16;
    return ua | (ub << 16);
}
__device__ inline float2 bf16x2(unsigned p) {
    return make_float2(__uint_as_float(p << 16), __uint_as_float(p & 0xffff0000u));
}

// ---------------- init: zero edge counters ----------------
__global__ __launch_bounds__(256) void k_init(int* cnt) {
    int i = blockIdx.x * 256 + threadIdx.x;
    if (i < N_NODES) cnt[i] = 0;
}

// ---------------- count edges per destination (row) ----------------
__global__ __launch_bounds__(256) void k_count(const int* __restrict__ row, int* cnt) {
    int e = blockIdx.x * 256 + threadIdx.x;
    if (e < N_EDGES) atomicAdd(&cnt[row[e]], 1);
}

// ---------------- dinv = rsqrt(cnt + 1)  (self-loop) ----------------
__global__ __launch_bounds__(256) void k_dinv(const int* __restrict__ cnt, float* dinv) {
    int i = blockIdx.x * 256 + threadIdx.x;
    if (i < N_NODES) dinv[i] = rsqrtf((float)(cnt[i] + 1));
}

// ---------------- graph start offsets via binary search (batch is sorted) ----------------
__global__ __launch_bounds__(256) void k_gbounds(const int* __restrict__ batch, int* gstart) {
    int g = blockIdx.x * 256 + threadIdx.x;
    if (g <= N_GRAPHS) {
        int lo = 0, hi = N_NODES;
        while (lo < hi) { int mid = (lo + hi) >> 1; if (batch[mid] < g) lo = mid + 1; else hi = mid; }
        gstart[g] = lo;
    }
}

// ---------------- exclusive scan of cnt -> offs (3 phases) ----------------
__global__ __launch_bounds__(256) void k_scan_a(const int* __restrict__ cnt, int* offs, int* bsums) {
    __shared__ int s[256];
    int b = blockIdx.x, t = threadIdx.x;
    int base = b * 1024 + t * 4;
    int v[4];
#pragma unroll
    for (int j = 0; j < 4; ++j) v[j] = (base + j < N_NODES) ? cnt[base + j] : 0;
    int local = v[0] + v[1] + v[2] + v[3];
    s[t] = local;
    __syncthreads();
    for (int off = 1; off < 256; off <<= 1) {
        int x = (t >= off) ? s[t - off] : 0;
        __syncthreads();
        s[t] += x;
        __syncthreads();
    }
    int run = s[t] - local;  // exclusive
#pragma unroll
    for (int j = 0; j < 4; ++j) {
        if (base + j < N_NODES) offs[base + j] = run;
        run += v[j];
    }
    if (t == 255) bsums[b] = s[255];
}

__global__ void k_scan_b(int* bsums, int nb) {
    if (threadIdx.x == 0 && blockIdx.x == 0) {
        int run = 0;
        for (int i = 0; i < nb; ++i) { int t = bsums[i]; bsums[i] = run; run += t; }
    }
}

__global__ __launch_bounds__(256) void k_scan_c(int* offs, const int* __restrict__ bsums, int* cursor) {
    int i = blockIdx.x * 256 + threadIdx.x;
    if (i < N_NODES) {
        int o = offs[i] + bsums[i >> 10];
        offs[i] = o;
        cursor[i] = o;
    }
}

// ---------------- fill CSR columns + per-edge norm weight ----------------
__global__ __launch_bounds__(256) void k_fill(const int* __restrict__ row, const int* __restrict__ col,
                                              const float* __restrict__ dinv,
                                              int* cursor, int* csr, float* wnorm) {
    int e = blockIdx.x * 256 + threadIdx.x;
    if (e < N_EDGES) {
        int r = row[e];
        int c = col[e];
        int pos = atomicAdd(&cursor[r], 1);
        csr[pos] = c;
        wnorm[pos] = dinv[r] * dinv[c];
    }
}

// ---------------- GEMM1: h1[50000,128](bf16) = X[50000,256] @ W[256,128] ----------------
#define BM 64
#define BK 16
__global__ __launch_bounds__(256) void k_gemm1(const float* __restrict__ X, const float* __restrict__ W,
                                               unsigned* __restrict__ h1u) {
    __shared__ float As[BM][BK + 1];
    __shared__ float Bs[BK][DIM1];
    int t = threadIdx.x;
    int tx = t & 15, ty = t >> 4;
    int rowBase = blockIdx.x * BM;
    float acc[4][8];
#pragma unroll
    for (int i = 0; i < 4; ++i)
#pragma unroll
        for (int j = 0; j < 8; ++j) acc[i][j] = 0.f;

    int ar = t >> 2, ak = (t & 3) * 4;        // A load: 64 rows x 16 k, float4
    int bk = t >> 4, bn = (t & 15) * 8;       // B load: 16 k x 128 n, 2x float4

    for (int k0 = 0; k0 < DIM0; k0 += BK) {
        int grow = rowBase + ar;
        float4 av = make_float4(0.f, 0.f, 0.f, 0.f);
        if (grow < N_NODES) av = *(const float4*)(X + (size_t)grow * DIM0 + k0 + ak);
        float4 bv0 = *(const float4*)(W + (size_t)(k0 + bk) * DIM1 + bn);
        float4 bv1 = *(const float4*)(W + (size_t)(k0 + bk) * DIM1 + bn + 4);
        __syncthreads();
        As[ar][ak + 0] = av.x; As[ar][ak + 1] = av.y; As[ar][ak + 2] = av.z; As[ar][ak + 3] = av.w;
        *(float4*)&Bs[bk][bn] = bv0;
        *(float4*)&Bs[bk][bn + 4] = bv1;
        __syncthreads();
#pragma unroll
        for (int kk = 0; kk < BK; ++kk) {
            float4 b0 = *(const float4*)&Bs[kk][tx * 4];
            float4 b1v = *(const float4*)&Bs[kk][64 + tx * 4];
#pragma unroll
            for (int i = 0; i < 4; ++i) {
                float a_ = As[ty * 4 + i][kk];
                acc[i][0] += a_ * b0.x;  acc[i][1] += a_ * b0.y;
                acc[i][2] += a_ * b0.z;  acc[i][3] += a_ * b0.w;
                acc[i][4] += a_ * b1v.x; acc[i][5] += a_ * b1v.y;
                acc[i][6] += a_ * b1v.z; acc[i][7] += a_ * b1v.w;
            }
        }
    }
#pragma unroll
    for (int i = 0; i < 4; ++i) {
        int row = rowBase + ty * 4 + i;
        if (row < N_NODES) {
            unsigned* hr = h1u + (size_t)row * 64;
            hr[tx * 2]      = bf16pack(acc[i][0], acc[i][1]);
            hr[tx * 2 + 1]  = bf16pack(acc[i][2], acc[i][3]);
            hr[32 + tx * 2]     = bf16pack(acc[i][4], acc[i][5]);
            hr[32 + tx * 2 + 1] = bf16pack(acc[i][6], acc[i][7]);
        }
    }
}

// ---------------- agg1: a1 = relu(Anorm @ h1 + b1), dim 128, bf16 gather ----------------
__global__ __launch_bounds__(256) void k_agg1(const unsigned* __restrict__ h1u, const float* __restrict__ dinv,
                                              const int* __restrict__ offs, const int* __restrict__ cnt,
                                              const int* __restrict__ csr, const float* __restrict__ wnorm,
                                              const float* __restrict__ b1, float* __restrict__ a1) {
    int node = blockIdx.x * 4 + (threadIdx.x >> 6);
    int lane = threadIdx.x & 63;
    float di = dinv[node];
    float sl = di * di;
    float2 vs = bf16x2(h1u[(size_t)node * 64 + lane]);
    float2 acc = make_float2(vs.x * sl, vs.y * sl);
    int s = offs[node], n = cnt[node];
    for (int base = 0; base < n; base += 64) {
        int m = min(64, n - base);
        int ec = 0; float ew = 0.f;
        if (lane < m) { ec = csr[s + base + lane]; ew = wnorm[s + base + lane]; }
        int j = 0;
        for (; j + 4 <= m; j += 4) {
            int c0 = __shfl(ec, j), c1 = __shfl(ec, j + 1), c2 = __shfl(ec, j + 2), c3 = __shfl(ec, j + 3);
            float w0 = __shfl(ew, j), w1 = __shfl(ew, j + 1), w2 = __shfl(ew, j + 2), w3 = __shfl(ew, j + 3);
            unsigned p0 = h1u[(size_t)c0 * 64 + lane];
            unsigned p1 = h1u[(size_t)c1 * 64 + lane];
            unsigned p2 = h1u[(size_t)c2 * 64 + lane];
            unsigned p3 = h1u[(size_t)c3 * 64 + lane];
            float2 v0 = bf16x2(p0), v1 = bf16x2(p1), v2 = bf16x2(p2), v3 = bf16x2(p3);
            acc.x += v0.x * w0 + v1.x * w1 + v2.x * w2 + v3.x * w3;
            acc.y += v0.y * w0 + v1.y * w1 + v2.y * w2 + v3.y * w3;
        }
        for (; j < m; ++j) {
            int c = __shfl(ec, j); float w = __shfl(ew, j);
            float2 v = bf16x2(h1u[(size_t)c * 64 + lane]);
            acc.x += v.x * w; acc.y += v.y * w;
        }
    }
    acc.x = fmaxf(acc.x + b1[2 * lane], 0.f);
    acc.y = fmaxf(acc.y + b1[2 * lane + 1], 0.f);
    ((float2*)a1)[(size_t)node * 64 + lane] = acc;
}

// ---------------- GEMM2: h2[50000,32](bf16) = a1[50000,128] @ W2[128,32] ----------------
#define AS2_LD 132
__global__ __launch_bounds__(256) void k_gemm2(const float* __restrict__ A, const float* __restrict__ W2,
                                               unsigned* __restrict__ h2u) {
    __shared__ float As2[16 * AS2_LD];
    __shared__ float W2s[DIM1 * DIM2];
    int t = threadIdx.x;
    int rb = blockIdx.x * 16;
    {
        int r = t >> 4, cb = (t & 15) * 8;
        const float* src = A + (size_t)(rb + r) * DIM1 + cb;
        *(float4*)&As2[r * AS2_LD + cb]     = *(const float4*)src;
        *(float4*)&As2[r * AS2_LD + cb + 4] = *(const float4*)(src + 4);
    }
    for (int i = t; i < 1024; i += 256) {
        *(float4*)&W2s[i * 4] = *(const float4*)(W2 + i * 4);
    }
    __syncthreads();
    int r = t >> 4, c2 = (t & 15) * 2;
    float a0 = 0.f, a1v = 0.f;
#pragma unroll 8
    for (int k = 0; k < DIM1; ++k) {
        float a_ = As2[r * AS2_LD + k];
        a0  += a_ * W2s[k * DIM2 + c2];
        a1v += a_ * W2s[k * DIM2 + c2 + 1];
    }
    h2u[(size_t)(rb + r) * 16 + (t & 15)] = bf16pack(a0, a1v);
}

// ---------------- agg2: a2 = Anorm @ h2 + b2, bf16 gather, 16 lanes/node ----------------
__global__ __launch_bounds__(256) void k_agg2(const unsigned* __restrict__ h2u, const float* __restrict__ dinv,
                                              const int* __restrict__ offs, const int* __restrict__ cnt,
                                              const int* __restrict__ csr, const float* __restrict__ wnorm,
                                              const float* __restrict__ b2, float* __restrict__ a2) {
    int t = threadIdx.x;
    int node = blockIdx.x * 16 + (t >> 4);
    int l = t & 15;
    float di = dinv[node];
    float sl = di * di;
    float2 vs = bf16x2(h2u[(size_t)node * 16 + l]);
    float2 acc = make_float2(vs.x * sl, vs.y * sl);
    int s = offs[node], n = cnt[node];
    for (int base = 0; base < n; base += 16) {
        int m = min(16, n - base);
        int ec = 0; float ew = 0.f;
        if (l < m) { ec = csr[s + base + l]; ew = wnorm[s + base + l]; }
        int j = 0;
        for (; j + 4 <= m; j += 4) {
            int c0 = __shfl(ec, j, 16), c1 = __shfl(ec, j + 1, 16);
            int c2 = __shfl(ec, j + 2, 16), c3 = __shfl(ec, j + 3, 16);
            float w0 = __shfl(ew, j, 16), w1 = __shfl(ew, j + 1, 16);
            float w2 = __shfl(ew, j + 2, 16), w3 = __shfl(ew, j + 3, 16);
            unsigned p0 = h2u[(size_t)c0 * 16 + l];
            unsigned p1 = h2u[(size_t)c1 * 16 + l];
            unsigned p2 = h2u[(size_t)c2 * 16 + l];
            unsigned p3 = h2u[(size_t)c3 * 16 + l];
            float2 v0 = bf16x2(p0), v1 = bf16x2(p1), v2 = bf16x2(p2), v3 = bf16x2(p3);
            acc.x += v0.x * w0 + v1.x * w1 + v2.x * w2 + v3.x * w3;
            acc.y += v0.y * w0 + v1.y * w1 + v2.y * w2 + v3.y * w3;
        }
        for (; j < m; ++j) {
            int c = __shfl(ec, j, 16); float w = __shfl(ew, j, 16);
            float2 v = bf16x2(h2u[(size_t)c * 16 + l]);
            acc.x += v.x * w; acc.y += v.y * w;
        }
    }
    acc.x += b2[2 * l];
    acc.y += b2[2 * l + 1];
    ((float2*)a2)[(size_t)node * 16 + l] = acc;
}

// ---------------- segmented mean-pool + log_softmax (1 block / graph) ----------------
__global__ __launch_bounds__(256) void k_pool(const float* __restrict__ a2, const int* __restrict__ gstart,
                                              float* __restrict__ out) {
    __shared__ float sred[8][DIM2];
    int g = blockIdx.x;
    int t = threadIdx.x;
    int s = gstart[g], e = gstart[g + 1];
    int d = t & 31, r = t >> 5;
    float acc = 0.f;
    for (int i = s + r; i < e; i += 8) acc += a2[(size_t)i * DIM2 + d];
    sred[r][d] = acc;
    __syncthreads();
    if (t < DIM2) {
        float sum = 0.f;
#pragma unroll
        for (int j = 0; j < 8; ++j) sum += sred[j][t];
        float cntf = fmaxf((float)(e - s), 1.0f);
        float val = sum / cntf;
        float v = val;
#pragma unroll
        for (int m = 16; m >= 1; m >>= 1) v = fmaxf(v, __shfl_xor(v, m, 32));
        float ex = expf(val - v);
#pragma unroll
        for (int m = 16; m >= 1; m >>= 1) ex += __shfl_xor(ex, m, 32);
        out[g * DIM2 + t] = val - v - logf(ex);
    }
}

extern "C" void kernel_launch(void* const* d_in, const int* in_sizes, int n_in,
                              void* d_out, int out_size, void* d_ws, size_t ws_size,
                              hipStream_t stream) {
    const float* x     = (const float*)d_in[0];
    const int*   eidx  = (const int*)d_in[1];
    const int*   batch = (const int*)d_in[2];
    const float* W1    = (const float*)d_in[3];
    const float* b1    = (const float*)d_in[4];
    const float* W2    = (const float*)d_in[5];
    const float* b2    = (const float*)d_in[6];
    const int* row = eidx;
    const int* col = eidx + N_EDGES;
    float* out = (float*)d_out;

    // workspace layout (16B aligned chunks)
    char* p = (char*)d_ws;
    float* dinv   = (float*)p; p += (size_t)N_NODES * 4;
    int*   cnt    = (int*)p;   p += (size_t)N_NODES * 4;
    int*   offs   = (int*)p;   p += (size_t)N_NODES * 4;
    int*   cursor = (int*)p;   p += (size_t)N_NODES * 4;
    int*   bsums  = (int*)p;   p += 256;
    int*   gstart = (int*)p;   p += 768;   // 129 ints, padded
    int*   csr    = (int*)p;   p += (size_t)N_EDGES * 4;
    float* wnorm  = (float*)p; p += (size_t)N_EDGES * 4;
    unsigned* h1u = (unsigned*)p; p += (size_t)N_NODES * 64 * 4;   // bf16 x2 packed, 12.8 MB
    float* a1     = (float*)p; p += (size_t)N_NODES * DIM1 * 4;    // 25.6 MB
    unsigned* h2u = (unsigned*)p; p += (size_t)N_NODES * 16 * 4;   // 3.2 MB
    float* a2     = (float*)p; p += (size_t)N_NODES * DIM2 * 4;    // 6.4 MB

    const int nb_nodes = (N_NODES + 255) / 256;       // 196
    const int nb_edges = (N_EDGES + 255) / 256;       // 3125
    const int nb_scan  = (N_NODES + 1023) / 1024;     // 49

    k_init<<<nb_nodes, 256, 0, stream>>>(cnt);
    k_count<<<nb_edges, 256, 0, stream>>>(row, cnt);
    k_dinv<<<nb_nodes, 256, 0, stream>>>(cnt, dinv);
    k_gbounds<<<1, 256, 0, stream>>>(batch, gstart);
    k_scan_a<<<nb_scan, 256, 0, stream>>>(cnt, offs, bsums);
    k_scan_b<<<1, 64, 0, stream>>>(bsums, nb_scan);
    k_scan_c<<<nb_nodes, 256, 0, stream>>>(offs, bsums, cursor);
    k_fill<<<nb_edges, 256, 0, stream>>>(row, col, dinv, cursor, csr, wnorm);

    k_gemm1<<<(N_NODES + BM - 1) / BM, 256, 0, stream>>>(x, W1, h1u);
    k_agg1<<<N_NODES / 4, 256, 0, stream>>>(h1u, dinv, offs, cnt, csr, wnorm, b1, a1);
    k_gemm2<<<N_NODES / 16, 256, 0, stream>>>(a1, W2, h2u);
    k_agg2<<<N_NODES / 16, 256, 0, stream>>>(h2u, dinv, offs, cnt, csr, wnorm, b2, a2);
    k_pool<<<N_GRAPHS, 256, 0, stream>>>(a2, gstart, out);
}

// Round 4
// 305.526 us; speedup vs baseline: 1.9532x; 1.1056x over previous
//
#include <hip/hip_runtime.h>
#include <math.h>

#define N_NODES 50000
#define N_EDGES 800000
#define N_GRAPHS 128
#define DIM0 256
#define DIM1 128
#define DIM2 32

using f32x4 = __attribute__((ext_vector_type(4))) float;
using s16x8 = __attribute__((ext_vector_type(8))) short;

// ---- bf16 pack/unpack helpers (RNE) ----
__device__ inline unsigned bf16pack(float a, float b) {
    unsigned ua = __float_as_uint(a), ub = __float_as_uint(b);
    ua = (ua + 0x7fffu + ((ua >> 16) & 1u)) >> 16;
    ub = (ub + 0x7fffu + ((ub >> 16) & 1u)) >> 16;
    return ua | (ub << 16);
}
__device__ inline float2 bf16x2(unsigned p) {
    return make_float2(__uint_as_float(p << 16), __uint_as_float(p & 0xffff0000u));
}

// ---------------- init: zero edge counters ----------------
__global__ __launch_bounds__(256) void k_init(int* cnt) {
    int i = blockIdx.x * 256 + threadIdx.x;
    if (i < N_NODES) cnt[i] = 0;
}

// ---------------- count edges per destination (row) ----------------
__global__ __launch_bounds__(256) void k_count(const int* __restrict__ row, int* cnt) {
    int e = blockIdx.x * 256 + threadIdx.x;
    if (e < N_EDGES) atomicAdd(&cnt[row[e]], 1);
}

// ---------------- dinv = rsqrt(cnt + 1)  (self-loop) ----------------
__global__ __launch_bounds__(256) void k_dinv(const int* __restrict__ cnt, float* dinv) {
    int i = blockIdx.x * 256 + threadIdx.x;
    if (i < N_NODES) dinv[i] = rsqrtf((float)(cnt[i] + 1));
}

// ---------------- graph start offsets via binary search (batch is sorted) ----------------
__global__ __launch_bounds__(256) void k_gbounds(const int* __restrict__ batch, int* gstart) {
    int g = blockIdx.x * 256 + threadIdx.x;
    if (g <= N_GRAPHS) {
        int lo = 0, hi = N_NODES;
        while (lo < hi) { int mid = (lo + hi) >> 1; if (batch[mid] < g) lo = mid + 1; else hi = mid; }
        gstart[g] = lo;
    }
}

// ---------------- exclusive scan of cnt -> offs (3 phases) ----------------
__global__ __launch_bounds__(256) void k_scan_a(const int* __restrict__ cnt, int* offs, int* bsums) {
    __shared__ int s[256];
    int b = blockIdx.x, t = threadIdx.x;
    int base = b * 1024 + t * 4;
    int v[4];
#pragma unroll
    for (int j = 0; j < 4; ++j) v[j] = (base + j < N_NODES) ? cnt[base + j] : 0;
    int local = v[0] + v[1] + v[2] + v[3];
    s[t] = local;
    __syncthreads();
    for (int off = 1; off < 256; off <<= 1) {
        int x = (t >= off) ? s[t - off] : 0;
        __syncthreads();
        s[t] += x;
        __syncthreads();
    }
    int run = s[t] - local;  // exclusive
#pragma unroll
    for (int j = 0; j < 4; ++j) {
        if (base + j < N_NODES) offs[base + j] = run;
        run += v[j];
    }
    if (t == 255) bsums[b] = s[255];
}

__global__ void k_scan_b(int* bsums, int nb) {
    if (threadIdx.x == 0 && blockIdx.x == 0) {
        int run = 0;
        for (int i = 0; i < nb; ++i) { int t = bsums[i]; bsums[i] = run; run += t; }
    }
}

__global__ __launch_bounds__(256) void k_scan_c(int* offs, const int* __restrict__ bsums, int* cursor) {
    int i = blockIdx.x * 256 + threadIdx.x;
    if (i < N_NODES) {
        int o = offs[i] + bsums[i >> 10];
        offs[i] = o;
        cursor[i] = o;
    }
}

// ---------------- fill CSR columns + per-edge norm weight ----------------
__global__ __launch_bounds__(256) void k_fill(const int* __restrict__ row, const int* __restrict__ col,
                                              const float* __restrict__ dinv,
                                              int* cursor, int* csr, float* wnorm) {
    int e = blockIdx.x * 256 + threadIdx.x;
    if (e < N_EDGES) {
        int r = row[e];
        int c = col[e];
        int pos = atomicAdd(&cursor[r], 1);
        csr[pos] = c;
        wnorm[pos] = dinv[r] * dinv[c];
    }
}

// ---------------- prepw: W1[256][128] fp32 -> W1b bf16 chunks in B-fragment order ----------------
// chunk c (0..4095): s=c>>9 (K-step), t=(c>>6)&7 (col tile), q=(c>>4)&3 (quad), n=c&15 (col in tile)
// chunk = 8 consecutive k = s*32+q*8.. for col t*16+n, packed as 4 uints (bf16 pairs).
__global__ __launch_bounds__(256) void k_prepw(const float* __restrict__ W1, uint* __restrict__ W1b) {
    int c = blockIdx.x * 256 + threadIdx.x;
    if (c >= 4096) return;
    int s = c >> 9, t = (c >> 6) & 7, q = (c >> 4) & 3, n = c & 15;
    int k0 = s * 32 + q * 8;
    int col = t * 16 + n;
    uint4 o;
    o.x = bf16pack(W1[(size_t)(k0 + 0) * DIM1 + col], W1[(size_t)(k0 + 1) * DIM1 + col]);
    o.y = bf16pack(W1[(size_t)(k0 + 2) * DIM1 + col], W1[(size_t)(k0 + 3) * DIM1 + col]);
    o.z = bf16pack(W1[(size_t)(k0 + 4) * DIM1 + col], W1[(size_t)(k0 + 5) * DIM1 + col]);
    o.w = bf16pack(W1[(size_t)(k0 + 6) * DIM1 + col], W1[(size_t)(k0 + 7) * DIM1 + col]);
    ((uint4*)W1b)[c] = o;
}

// ---------------- GEMM1 (MFMA bf16): h1[50000,128] = X[50000,256] @ W1 ----------------
// h1u feature permutation: uint j = u*16+c holds features (32u+c, 32u+c+16).
#define G1_BM 128
#define AS_LD 20  // uints per row (16 data + 4 pad = 80 B, 16B-aligned, 2-way banks = free)
__global__ __launch_bounds__(256) void k_gemm1(const float* __restrict__ X, const uint* __restrict__ W1b,
                                               unsigned* __restrict__ h1u) {
    __shared__ uint w1s[16384];        // 64 KB: full W1 in B-frag order
    __shared__ uint As[G1_BM * AS_LD]; // 10 KB: A tile bf16, one K-step
    int t = threadIdx.x;
    int w = t >> 6, lane = t & 63, q = lane >> 4, m16 = lane & 15;
    int rowBase = blockIdx.x * G1_BM;

    // load full W1b into LDS (coalesced uint4)
    {
        const uint4* src = (const uint4*)W1b;
        uint4* dst = (uint4*)w1s;
#pragma unroll
        for (int i = 0; i < 16; ++i) dst[i * 256 + t] = src[i * 256 + t];
    }

    f32x4 acc[2][8];
#pragma unroll
    for (int i = 0; i < 2; ++i)
#pragma unroll
        for (int j = 0; j < 8; ++j) acc[i][j] = (f32x4){0.f, 0.f, 0.f, 0.f};

    int ar = t >> 1, ah = t & 1;  // staging: row ar, k-half ah (16 floats)
    for (int s = 0; s < 8; ++s) {
        // stage A tile (128 rows x 32 k) as bf16
        float4 f0 = {0,0,0,0}, f1 = {0,0,0,0}, f2 = {0,0,0,0}, f3 = {0,0,0,0};
        int grow = rowBase + ar;
        if (grow < N_NODES) {
            const float* src = X + (size_t)grow * DIM0 + s * 32 + ah * 16;
            f0 = *(const float4*)(src + 0);
            f1 = *(const float4*)(src + 4);
            f2 = *(const float4*)(src + 8);
            f3 = *(const float4*)(src + 12);
        }
        uint4 p0, p1;
        p0.x = bf16pack(f0.x, f0.y); p0.y = bf16pack(f0.z, f0.w);
        p0.z = bf16pack(f1.x, f1.y); p0.w = bf16pack(f1.z, f1.w);
        p1.x = bf16pack(f2.x, f2.y); p1.y = bf16pack(f2.z, f2.w);
        p1.z = bf16pack(f3.x, f3.y); p1.w = bf16pack(f3.z, f3.w);
        __syncthreads();  // protect As from previous iteration's readers
        *(uint4*)&As[ar * AS_LD + ah * 8 + 0] = p0;
        *(uint4*)&As[ar * AS_LD + ah * 8 + 4] = p1;
        __syncthreads();

        s16x8 af[2];
#pragma unroll
        for (int rt = 0; rt < 2; ++rt) {
            int arow = w * 32 + rt * 16 + m16;
            af[rt] = *(s16x8*)&As[arow * AS_LD + q * 4];
        }
#pragma unroll
        for (int tt = 0; tt < 8; ++tt) {
            s16x8 bf = *(s16x8*)&w1s[((s * 8 + tt) * 64 + lane) * 4];
            acc[0][tt] = __builtin_amdgcn_mfma_f32_16x16x32_bf16(af[0], bf, acc[0][tt], 0, 0, 0);
            acc[1][tt] = __builtin_amdgcn_mfma_f32_16x16x32_bf16(af[1], bf, acc[1][tt], 0, 0, 0);
        }
    }

    // epilogue: C layout col=lane&15, row=q*4+reg; pack col pairs across tiles (2u, 2u+1)
#pragma unroll
    for (int rt = 0; rt < 2; ++rt) {
#pragma unroll
        for (int reg = 0; reg < 4; ++reg) {
            int row = rowBase + w * 32 + rt * 16 + q * 4 + reg;
            if (row < N_NODES) {
                unsigned* hr = h1u + (size_t)row * 64;
#pragma unroll
                for (int u = 0; u < 4; ++u)
                    hr[u * 16 + m16] = bf16pack(acc[rt][2 * u][reg], acc[rt][2 * u + 1][reg]);
            }
        }
    }
}

// ---------------- agg1: a1 = relu(Anorm @ h1 + b1), dim 128, bf16 gather ----------------
// h1u uint j holds features (32*(j>>4)+(j&15), +16); a1 position 2j/2j+1 follows same order.
__global__ __launch_bounds__(256) void k_agg1(const unsigned* __restrict__ h1u, const float* __restrict__ dinv,
                                              const int* __restrict__ offs, const int* __restrict__ cnt,
                                              const int* __restrict__ csr, const float* __restrict__ wnorm,
                                              const float* __restrict__ b1, float* __restrict__ a1) {
    int node = blockIdx.x * 4 + (threadIdx.x >> 6);
    int lane = threadIdx.x & 63;
    float di = dinv[node];
    float sl = di * di;
    float2 vs = bf16x2(h1u[(size_t)node * 64 + lane]);
    float2 acc = make_float2(vs.x * sl, vs.y * sl);
    int s = offs[node], n = cnt[node];
    for (int base = 0; base < n; base += 64) {
        int m = min(64, n - base);
        int ec = 0; float ew = 0.f;
        if (lane < m) { ec = csr[s + base + lane]; ew = wnorm[s + base + lane]; }
        int j = 0;
        for (; j + 4 <= m; j += 4) {
            int c0 = __shfl(ec, j), c1 = __shfl(ec, j + 1), c2 = __shfl(ec, j + 2), c3 = __shfl(ec, j + 3);
            float w0 = __shfl(ew, j), w1 = __shfl(ew, j + 1), w2 = __shfl(ew, j + 2), w3 = __shfl(ew, j + 3);
            unsigned p0 = h1u[(size_t)c0 * 64 + lane];
            unsigned p1 = h1u[(size_t)c1 * 64 + lane];
            unsigned p2 = h1u[(size_t)c2 * 64 + lane];
            unsigned p3 = h1u[(size_t)c3 * 64 + lane];
            float2 v0 = bf16x2(p0), v1 = bf16x2(p1), v2 = bf16x2(p2), v3 = bf16x2(p3);
            acc.x += v0.x * w0 + v1.x * w1 + v2.x * w2 + v3.x * w3;
            acc.y += v0.y * w0 + v1.y * w1 + v2.y * w2 + v3.y * w3;
        }
        for (; j < m; ++j) {
            int c = __shfl(ec, j); float w = __shfl(ew, j);
            float2 v = bf16x2(h1u[(size_t)c * 64 + lane]);
            acc.x += v.x * w; acc.y += v.y * w;
        }
    }
    int f0 = (lane >> 4) * 32 + (lane & 15);
    acc.x = fmaxf(acc.x + b1[f0], 0.f);
    acc.y = fmaxf(acc.y + b1[f0 + 16], 0.f);
    ((float2*)a1)[(size_t)node * 64 + lane] = acc;
}

// ---------------- GEMM2: h2[50000,32](bf16) = a1[50000,128] @ W2[128,32] ----------------
// a1 is feature-permuted: W2 rows permuted to match at LDS load.
#define AS2_LD 132
__global__ __launch_bounds__(256) void k_gemm2(const float* __restrict__ A, const float* __restrict__ W2,
                                               unsigned* __restrict__ h2u) {
    __shared__ float As2[16 * AS2_LD];
    __shared__ float W2s[DIM1 * DIM2];
    int t = threadIdx.x;
    int rb = blockIdx.x * 16;
    {
        int r = t >> 4, cb = (t & 15) * 8;
        const float* src = A + (size_t)(rb + r) * DIM1 + cb;
        *(float4*)&As2[r * AS2_LD + cb]     = *(const float4*)src;
        *(float4*)&As2[r * AS2_LD + cb + 4] = *(const float4*)(src + 4);
    }
    for (int i = t; i < 1024; i += 256) {
        int k = i >> 3, c4 = (i & 7) * 4;
        int pos = 2 * ((k >> 5) * 16 + (k & 15)) + ((k >> 4) & 1);
        *(float4*)&W2s[pos * DIM2 + c4] = *(const float4*)(W2 + (size_t)k * DIM2 + c4);
    }
    __syncthreads();
    int r = t >> 4, c2 = (t & 15) * 2;
    float a0 = 0.f, a1v = 0.f;
#pragma unroll 8
    for (int k = 0; k < DIM1; ++k) {
        float a_ = As2[r * AS2_LD + k];
        a0  += a_ * W2s[k * DIM2 + c2];
        a1v += a_ * W2s[k * DIM2 + c2 + 1];
    }
    h2u[(size_t)(rb + r) * 16 + (t & 15)] = bf16pack(a0, a1v);
}

// ---------------- agg2: a2 = Anorm @ h2 + b2, bf16 gather, 16 lanes/node ----------------
__global__ __launch_bounds__(256) void k_agg2(const unsigned* __restrict__ h2u, const float* __restrict__ dinv,
                                              const int* __restrict__ offs, const int* __restrict__ cnt,
                                              const int* __restrict__ csr, const float* __restrict__ wnorm,
                                              const float* __restrict__ b2, float* __restrict__ a2) {
    int t = threadIdx.x;
    int node = blockIdx.x * 16 + (t >> 4);
    int l = t & 15;
    float di = dinv[node];
    float sl = di * di;
    float2 vs = bf16x2(h2u[(size_t)node * 16 + l]);
    float2 acc = make_float2(vs.x * sl, vs.y * sl);
    int s = offs[node], n = cnt[node];
    for (int base = 0; base < n; base += 16) {
        int m = min(16, n - base);
        int ec = 0; float ew = 0.f;
        if (l < m) { ec = csr[s + base + l]; ew = wnorm[s + base + l]; }
        int j = 0;
        for (; j + 4 <= m; j += 4) {
            int c0 = __shfl(ec, j, 16), c1 = __shfl(ec, j + 1, 16);
            int c2 = __shfl(ec, j + 2, 16), c3 = __shfl(ec, j + 3, 16);
            float w0 = __shfl(ew, j, 16), w1 = __shfl(ew, j + 1, 16);
            float w2 = __shfl(ew, j + 2, 16), w3 = __shfl(ew, j + 3, 16);
            unsigned p0 = h2u[(size_t)c0 * 16 + l];
            unsigned p1 = h2u[(size_t)c1 * 16 + l];
            unsigned p2 = h2u[(size_t)c2 * 16 + l];
            unsigned p3 = h2u[(size_t)c3 * 16 + l];
            float2 v0 = bf16x2(p0), v1 = bf16x2(p1), v2 = bf16x2(p2), v3 = bf16x2(p3);
            acc.x += v0.x * w0 + v1.x * w1 + v2.x * w2 + v3.x * w3;
            acc.y += v0.y * w0 + v1.y * w1 + v2.y * w2 + v3.y * w3;
        }
        for (; j < m; ++j) {
            int c = __shfl(ec, j, 16); float w = __shfl(ew, j, 16);
            float2 v = bf16x2(h2u[(size_t)c * 16 + l]);
            acc.x += v.x * w; acc.y += v.y * w;
        }
    }
    acc.x += b2[2 * l];
    acc.y += b2[2 * l + 1];
    ((float2*)a2)[(size_t)node * 16 + l] = acc;
}

// ---------------- segmented mean-pool + log_softmax (1 block / graph) ----------------
__global__ __launch_bounds__(256) void k_pool(const float* __restrict__ a2, const int* __restrict__ gstart,
                                              float* __restrict__ out) {
    __shared__ float sred[8][DIM2];
    int g = blockIdx.x;
    int t = threadIdx.x;
    int s = gstart[g], e = gstart[g + 1];
    int d = t & 31, r = t >> 5;
    float acc = 0.f;
    for (int i = s + r; i < e; i += 8) acc += a2[(size_t)i * DIM2 + d];
    sred[r][d] = acc;
    __syncthreads();
    if (t < DIM2) {
        float sum = 0.f;
#pragma unroll
        for (int j = 0; j < 8; ++j) sum += sred[j][t];
        float cntf = fmaxf((float)(e - s), 1.0f);
        float val = sum / cntf;
        float v = val;
#pragma unroll
        for (int m = 16; m >= 1; m >>= 1) v = fmaxf(v, __shfl_xor(v, m, 32));
        float ex = expf(val - v);
#pragma unroll
        for (int m = 16; m >= 1; m >>= 1) ex += __shfl_xor(ex, m, 32);
        out[g * DIM2 + t] = val - v - logf(ex);
    }
}

extern "C" void kernel_launch(void* const* d_in, const int* in_sizes, int n_in,
                              void* d_out, int out_size, void* d_ws, size_t ws_size,
                              hipStream_t stream) {
    const float* x     = (const float*)d_in[0];
    const int*   eidx  = (const int*)d_in[1];
    const int*   batch = (const int*)d_in[2];
    const float* W1    = (const float*)d_in[3];
    const float* b1    = (const float*)d_in[4];
    const float* W2    = (const float*)d_in[5];
    const float* b2    = (const float*)d_in[6];
    const int* row = eidx;
    const int* col = eidx + N_EDGES;
    float* out = (float*)d_out;

    // workspace layout (16B aligned chunks)
    char* p = (char*)d_ws;
    float* dinv   = (float*)p; p += (size_t)N_NODES * 4;
    int*   cnt    = (int*)p;   p += (size_t)N_NODES * 4;
    int*   offs   = (int*)p;   p += (size_t)N_NODES * 4;
    int*   cursor = (int*)p;   p += (size_t)N_NODES * 4;
    int*   bsums  = (int*)p;   p += 256;
    int*   gstart = (int*)p;   p += 768;   // 129 ints, padded
    uint*  W1b    = (uint*)p;  p += 4096 * 16;  // 64 KB swizzled bf16 W1
    int*   csr    = (int*)p;   p += (size_t)N_EDGES * 4;
    float* wnorm  = (float*)p; p += (size_t)N_EDGES * 4;
    unsigned* h1u = (unsigned*)p; p += (size_t)N_NODES * 64 * 4;   // bf16 x2 packed, 12.8 MB
    float* a1     = (float*)p; p += (size_t)N_NODES * DIM1 * 4;    // 25.6 MB
    unsigned* h2u = (unsigned*)p; p += (size_t)N_NODES * 16 * 4;   // 3.2 MB
    float* a2     = (float*)p; p += (size_t)N_NODES * DIM2 * 4;    // 6.4 MB

    const int nb_nodes = (N_NODES + 255) / 256;       // 196
    const int nb_edges = (N_EDGES + 255) / 256;       // 3125
    const int nb_scan  = (N_NODES + 1023) / 1024;     // 49

    k_init<<<nb_nodes, 256, 0, stream>>>(cnt);
    k_count<<<nb_edges, 256, 0, stream>>>(row, cnt);
    k_dinv<<<nb_nodes, 256, 0, stream>>>(cnt, dinv);
    k_gbounds<<<1, 256, 0, stream>>>(batch, gstart);
    k_prepw<<<16, 256, 0, stream>>>(W1, W1b);
    k_scan_a<<<nb_scan, 256, 0, stream>>>(cnt, offs, bsums);
    k_scan_b<<<1, 64, 0, stream>>>(bsums, nb_scan);
    k_scan_c<<<nb_nodes, 256, 0, stream>>>(offs, bsums, cursor);
    k_fill<<<nb_edges, 256, 0, stream>>>(row, col, dinv, cursor, csr, wnorm);

    k_gemm1<<<(N_NODES + G1_BM - 1) / G1_BM, 256, 0, stream>>>(x, W1b, h1u);
    k_agg1<<<N_NODES / 4, 256, 0, stream>>>(h1u, dinv, offs, cnt, csr, wnorm, b1, a1);
    k_gemm2<<<N_NODES / 16, 256, 0, stream>>>(a1, W2, h2u);
    k_agg2<<<N_NODES / 16, 256, 0, stream>>>(h2u, dinv, offs, cnt, csr, wnorm, b2, a2);
    k_pool<<<N_GRAPHS, 256, 0, stream>>>(a2, gstart, out);
}